// Round 6
// baseline (70669.470 us; speedup 1.0000x reference)
//
#include <hip/hip_runtime.h>
#include <stdint.h>

// TLSTM: batch-1 LSTM, T=16384 steps, IN=512, H=1024, OUT=64.
// Persistent-kernel design: 256 WGs (one per CU). WG b owns h-elements
// {4b..4b+3}; wave w owns element 4b+w and computes all 4 gate rows for
// it; weights live in registers (96 floats/lane, loaded once). Cross-WG
// exchange of h each step through a tagged 64-bit {step, value} word per
// h-element in d_ws, double-buffered by step parity.
//
// Experiment ledger:
//   R1: coalesced 2x16B poll sweeps            35.0 -> 29.0 ms
//   R2: pipelined vmcnt poll + x-in-regs       -> 90+ ms (foreign HBM
//       loads inside the poll's counted-vmcnt window)
//   R3: 4B words (8KB footprint)               -> 36.5 ms (L3 line/
//       channel parallelism halved; keep 8B words / 16KB spread)
//   R4: s_sleep-paced single-slot poll         -> 29.0 ms == R1 exactly
//       => poll is latency-bound, not pressure-bound
//   R5: A/B counted-vmcnt(2) poll + x-regs     -> bench crashed (infra
//       or hang; counted-vmcnt poll abandoned as fragile)
// R6 (this): poll byte-identical to R1 (issue -> vmcnt(0) -> check).
// Single change: x staging moved OFF the pre-poll path. x[t+1] is
// prefetched to regs post-barrier and staged to LDS post-barrier of the
// NEXT step from a full-step-old register (vmcnt(0) there is ~free and
// also absorbs the aged producer store). The poll window contains no
// foreign latency: not the X fetch (R1 paid ~200-400cy L2/L3 here), not
// the store drain.

typedef unsigned long long u64;
typedef uint32_t u32x2 __attribute__((ext_vector_type(2)));
typedef uint32_t u32x4 __attribute__((ext_vector_type(4)));

#define T_STEPS 16384
#define IN_DIM  512
#define H_DIM   1024
#define OUT_DIM 64
#define NWG     256

__device__ __forceinline__ float sigf(float x) {
    return 1.0f / (1.0f + __expf(-x));
}
__device__ __forceinline__ float tanh_fast(float x) {
    // tanh(x) = 2*sigmoid(2x) - 1 ; |err| ~1e-7 rel with __expf
    return 2.0f / (1.0f + __expf(-2.0f * x)) - 1.0f;
}

__global__ __launch_bounds__(256, 1) void lstm_seq(
    const float* __restrict__ X,
    const float* __restrict__ W_ih,
    const float* __restrict__ W_hh,
    const float* __restrict__ b_ih,
    const float* __restrict__ b_hh,
    u64* __restrict__ hbuf)   // [2][H_DIM] tagged words in d_ws
{
    const int b    = blockIdx.x;      // 0..255
    const int tid  = threadIdx.x;     // 0..255
    const int w    = tid >> 6;        // wave id == owned element index j
    const int lane = tid & 63;
    const int elem = 4 * b + w;       // global h index this wave produces

    __shared__ float h_lds[2][H_DIM];
    __shared__ float x_lds[2][IN_DIM];

    // ---- one-time: weights into registers ----
    float4 wh[4][4];   // [gate][chunk]  over H_DIM=1024
    float4 wx[4][2];   // [gate][chunk]  over IN_DIM=512
    float  bias_g[4];
    #pragma unroll
    for (int g = 0; g < 4; ++g) {
        const int row = g * H_DIM + elem;
        #pragma unroll
        for (int c = 0; c < 4; ++c)
            wh[g][c] = *(const float4*)(W_hh + (size_t)row * H_DIM + (c * 256 + lane * 4));
        #pragma unroll
        for (int c = 0; c < 2; ++c)
            wx[g][c] = *(const float4*)(W_ih + (size_t)row * IN_DIM + (c * 256 + lane * 4));
        bias_g[g] = b_ih[row] + b_hh[row];
    }
    // Force the compiler to drain the weight loads HERE (pre-loop), so no
    // compiler-inserted vmcnt wait can land inside the loop body where our
    // asm loads would inflate it (R2 lesson).
    {
        float wsum = bias_g[0] + bias_g[1] + bias_g[2] + bias_g[3];
        #pragma unroll
        for (int g = 0; g < 4; ++g) {
            #pragma unroll
            for (int c = 0; c < 4; ++c)
                wsum += wh[g][c].x + wh[g][c].y + wh[g][c].z + wh[g][c].w;
            #pragma unroll
            for (int c = 0; c < 2; ++c)
                wsum += wx[g][c].x + wx[g][c].y + wx[g][c].z + wx[g][c].w;
        }
        asm volatile("" :: "v"(wsum));
    }

    // per-thread poll bases for the two parity buffers (4 tagged words = 32B)
    const uint32_t* poll0 = (const uint32_t*)(hbuf + (size_t)tid * 4);
    const uint32_t* poll1 = (const uint32_t*)(hbuf + (size_t)H_DIM + (size_t)tid * 4);

    // ---- pre-loop: stage x_lds[0] = X[0]; prefetch X[1] into regs ----
    u32x2 xc;
    {
        const float* xp = X + (size_t)tid * 2;
        asm volatile("global_load_dwordx2 %0, %1, off"
                     : "=v"(xc) : "v"(xp) : "memory");
        asm volatile("s_waitcnt vmcnt(0)" : "+v"(xc) :: "memory");
        x_lds[0][tid * 2 + 0] = __uint_as_float(xc[0]);
        x_lds[0][tid * 2 + 1] = __uint_as_float(xc[1]);
        const float* xp1 = X + (size_t)IN_DIM + tid * 2;
        asm volatile("global_load_dwordx2 %0, %1, off"
                     : "=v"(xc) : "v"(xp1) : "memory");
    }

    float c_state = 0.0f;   // cell state for `elem` (consistent across lanes)

    for (int t = 0; t < T_STEPS; ++t) {
        const int p = t & 1;

        // ---- poll h[t]: R1-exact single-slot poll. Poll window contains
        //      only poll loads (+ step-old completed xc / aged store,
        //      both older in issue order -> hidden by in-order drain) ----
        {
            const uint32_t* src = p ? poll1 : poll0;
            const uint32_t tu = (uint32_t)t;
            u32x4 a, b4;
            for (;;) {
                asm volatile(
                    "global_load_dwordx4 %0, %2, off sc0 sc1\n\t"
                    "global_load_dwordx4 %1, %2, off offset:16 sc0 sc1\n\t"
                    "s_waitcnt vmcnt(0)"
                    : "=&v"(a), "=&v"(b4)
                    : "v"(src)
                    : "memory");
                // dwords: [val0, tag0, val1, tag1]
                if ((((a[1] ^ tu) | (a[3] ^ tu)) | ((b4[1] ^ tu) | (b4[3] ^ tu))) == 0u)
                    break;
            }
            h_lds[p][tid * 4 + 0] = __uint_as_float(a[0]);
            h_lds[p][tid * 4 + 1] = __uint_as_float(a[2]);
            h_lds[p][tid * 4 + 2] = __uint_as_float(b4[0]);
            h_lds[p][tid * 4 + 3] = __uint_as_float(b4[2]);
        }
        __syncthreads();   // single barrier per step: h staging complete

        // ---- stage x[t+1] from the step-old register prefetch, then
        //      issue the X[t+2] prefetch. Post-barrier writes to parity
        //      (t+1)&1 are race-free: that buffer is only read after the
        //      NEXT barrier. vmcnt(0) is ~free (xc issued a full step
        //      ago) and absorbs the aged producer store. ----
        asm volatile("s_waitcnt vmcnt(0)" : "+v"(xc) :: "memory");
        x_lds[(t + 1) & 1][tid * 2 + 0] = __uint_as_float(xc[0]);
        x_lds[(t + 1) & 1][tid * 2 + 1] = __uint_as_float(xc[1]);
        {
            const int nr = (t + 2 < T_STEPS) ? t + 2 : T_STEPS - 1;
            const float* xp = X + (size_t)nr * IN_DIM + tid * 2;
            asm volatile("global_load_dwordx2 %0, %1, off"
                         : "=v"(xc) : "v"(xp) : "memory");
        }

        // ---- 4 gate dot-products for `elem` ----
        float acc0 = 0.f, acc1 = 0.f, acc2 = 0.f, acc3 = 0.f;
        const float4* h4 = (const float4*)(&h_lds[p][0]);
        const float4* x4 = (const float4*)(&x_lds[p][0]);
        #pragma unroll
        for (int c = 0; c < 4; ++c) {
            const float4 hv = h4[c * 64 + lane];
            acc0 += wh[0][c].x*hv.x + wh[0][c].y*hv.y + wh[0][c].z*hv.z + wh[0][c].w*hv.w;
            acc1 += wh[1][c].x*hv.x + wh[1][c].y*hv.y + wh[1][c].z*hv.z + wh[1][c].w*hv.w;
            acc2 += wh[2][c].x*hv.x + wh[2][c].y*hv.y + wh[2][c].z*hv.z + wh[2][c].w*hv.w;
            acc3 += wh[3][c].x*hv.x + wh[3][c].y*hv.y + wh[3][c].z*hv.z + wh[3][c].w*hv.w;
        }
        #pragma unroll
        for (int c = 0; c < 2; ++c) {
            const float4 qv = x4[c * 64 + lane];
            acc0 += wx[0][c].x*qv.x + wx[0][c].y*qv.y + wx[0][c].z*qv.z + wx[0][c].w*qv.w;
            acc1 += wx[1][c].x*qv.x + wx[1][c].y*qv.y + wx[1][c].z*qv.z + wx[1][c].w*qv.w;
            acc2 += wx[2][c].x*qv.x + wx[2][c].y*qv.y + wx[2][c].z*qv.z + wx[2][c].w*qv.w;
            acc3 += wx[3][c].x*qv.x + wx[3][c].y*qv.y + wx[3][c].z*qv.z + wx[3][c].w*qv.w;
        }

        // ---- full-wave butterfly reduce (all lanes end with the sums) ----
        #pragma unroll
        for (int off = 32; off >= 1; off >>= 1) {
            acc0 += __shfl_xor(acc0, off);
            acc1 += __shfl_xor(acc1, off);
            acc2 += __shfl_xor(acc2, off);
            acc3 += __shfl_xor(acc3, off);
        }

        // ---- combine (all lanes compute; avoids divergent exec region) ----
        const float ii = sigf(acc0 + bias_g[0]);
        const float ff = sigf(acc1 + bias_g[1]);
        const float gg = tanh_fast(acc2 + bias_g[2]);
        const float oo = sigf(acc3 + bias_g[3]);
        const float cn = ff * c_state + ii * gg;
        c_state = cn;
        const float hn = oo * tanh_fast(cn);

        if (lane == 0) {
            const u64 word = ((u64)(unsigned)(t + 1) << 32)
                           | (u64)__float_as_uint(hn);
            __hip_atomic_store(hbuf + (size_t)((t + 1) & 1) * H_DIM + elem,
                               word, __ATOMIC_RELAXED, __HIP_MEMORY_SCOPE_AGENT);
        }
        // No second barrier needed: next-step staging writes parity (t+1)&1,
        // disjoint from this step's reads; tag protocol covers parity reuse.
    }
}

__global__ __launch_bounds__(256, 1) void lstm_head(
    const u64* __restrict__ hbuf,
    const float* __restrict__ W_lin,
    const float* __restrict__ b_lin,
    float* __restrict__ out)
{
    const int tid  = threadIdx.x;
    const int o    = tid >> 2;       // output index, 4 threads per output
    const int part = tid & 3;
    const u64* src = hbuf + (size_t)(T_STEPS & 1) * H_DIM;  // buf[0]: tag T

    float sum = 0.f;
    const int k0 = part * 256;
    for (int k = k0; k < k0 + 256; k += 4) {
        const float4 wv = *(const float4*)(W_lin + (size_t)o * H_DIM + k);
        sum += wv.x * __uint_as_float((unsigned)src[k + 0])
             + wv.y * __uint_as_float((unsigned)src[k + 1])
             + wv.z * __uint_as_float((unsigned)src[k + 2])
             + wv.w * __uint_as_float((unsigned)src[k + 3]);
    }
    sum += __shfl_xor(sum, 1);
    sum += __shfl_xor(sum, 2);
    if (part == 0)
        out[o] = 1.0f / (1.0f + __expf(-(sum + b_lin[o])));
}

extern "C" void kernel_launch(void* const* d_in, const int* in_sizes, int n_in,
                              void* d_out, int out_size, void* d_ws, size_t ws_size,
                              hipStream_t stream) {
    const float* X     = (const float*)d_in[0];
    // d_in[1] Mask, d_in[2] Delta, d_in[3] dt: unused by the forward pass
    const float* W_ih  = (const float*)d_in[4];
    const float* W_hh  = (const float*)d_in[5];
    const float* b_ih  = (const float*)d_in[6];
    const float* b_hh  = (const float*)d_in[7];
    const float* W_lin = (const float*)d_in[8];
    const float* b_lin = (const float*)d_in[9];
    float* out = (float*)d_out;

    u64* hbuf = (u64*)d_ws;   // 2 * 1024 * 8B = 16 KiB used

    // init: both parity buffers = {tag=0, h=0.0f} (all zero bytes)
    hipMemsetAsync(hbuf, 0, 2 * H_DIM * sizeof(u64), stream);

    lstm_seq<<<NWG, 256, 0, stream>>>(X, W_ih, W_hh, b_ih, b_hh, hbuf);
    lstm_head<<<1, 256, 0, stream>>>(hbuf, W_lin, b_lin, out);
}

// Round 7
// 31137.418 us; speedup vs baseline: 2.2696x; 2.2696x over previous
//
#include <hip/hip_runtime.h>
#include <stdint.h>

// TLSTM: batch-1 LSTM, T=16384 steps, IN=512, H=1024, OUT=64.
// Persistent-kernel design: 256 WGs (one per CU). WG b owns h-elements
// {4b..4b+3}; wave w owns element 4b+w and computes all 4 gate rows for
// it; weights live in registers (96 floats/lane, loaded once). Cross-WG
// exchange of h each step through a tagged 64-bit {step, value} word per
// h-element in d_ws, double-buffered by step parity.
//
// Experiment ledger:
//   R1: coalesced 2x16B poll sweeps            35.0 -> 29.0 ms
//   R2: pipelined vmcnt poll + x-in-regs       -> 90+ ms (foreign HBM
//       loads inside the poll's counted-vmcnt window)
//   R3: 4B words (8KB footprint)               -> 36.5 ms (same requests
//       onto HALF the L3 lines -> per-line rate doubled)
//   R4: s_sleep-paced single-slot poll         -> 29.0 ms == R1 exactly
//   R5: A/B counted-vmcnt(2) poll              -> crashed; abandoned
//   R6: x-staging moved off pre-poll path      -> 67.6 ms, FETCH 4x
//       => R1's pre-poll x-fetch delay is LOAD-BEARING: it makes the
//          first sample land after stores are visible. Restored.
// Model: all WGs poll the SAME 128 L3 lines; the owning banks serialize
// hundreds of requests/line/sweep -> bank service time IS the observed
// poll "RTT". Every delta so far tracks per-line request rate.
// R7 (this): keep R1 step structure byte-identical; cut per-line rate:
//   (a) 8x hbuf replication: producers store to 8 replicas (8 relaxed
//       8B stores, fire-and-forget); WG b polls replica b&7 only
//       -> per-line consumer rate /8 (32 WGs/line).
//   (b) contiguous poll sweep: two 16B loads per thread over two
//       contiguous 4KB blocks (wave-instr touches 16 lines once, vs
//       stride-32's 32 lines twice) -> per-line rate /2 more.
//       Thread tid stages elements {2tid,2tid+1,512+2tid,512+2tid+1}.

typedef unsigned long long u64;
typedef uint32_t u32;
typedef uint32_t u32x4 __attribute__((ext_vector_type(4)));

#define T_STEPS 16384
#define IN_DIM  512
#define H_DIM   1024
#define OUT_DIM 64
#define NWG     256
#define NREP    8

__device__ __forceinline__ float sigf(float x) {
    return 1.0f / (1.0f + __expf(-x));
}
__device__ __forceinline__ float tanh_fast(float x) {
    // tanh(x) = 2*sigmoid(2x) - 1 ; |err| ~1e-7 rel with __expf
    return 2.0f / (1.0f + __expf(-2.0f * x)) - 1.0f;
}

__global__ __launch_bounds__(256, 1) void lstm_seq(
    const float* __restrict__ X,
    const float* __restrict__ W_ih,
    const float* __restrict__ W_hh,
    const float* __restrict__ b_ih,
    const float* __restrict__ b_hh,
    u64* __restrict__ hbuf)   // [NREP][2][H_DIM] tagged words in d_ws
{
    const int b    = blockIdx.x;      // 0..255
    const int tid  = threadIdx.x;     // 0..255
    const int w    = tid >> 6;        // wave id == owned element index j
    const int lane = tid & 63;
    const int elem = 4 * b + w;       // global h index this wave produces
    const int rep  = b & (NREP - 1);  // which replica this WG polls

    __shared__ float h_lds[2][H_DIM];
    __shared__ float x_lds[2][IN_DIM];

    // ---- one-time: weights into registers ----
    // lane covers k = c*256 + lane*4 + {0..3}  (contiguous float4, coalesced
    // global loads and conflict-free ds_read_b128 later).
    float4 wh[4][4];   // [gate][chunk]  over H_DIM=1024
    float4 wx[4][2];   // [gate][chunk]  over IN_DIM=512
    float  bias_g[4];
    #pragma unroll
    for (int g = 0; g < 4; ++g) {
        const int row = g * H_DIM + elem;
        #pragma unroll
        for (int c = 0; c < 4; ++c)
            wh[g][c] = *(const float4*)(W_hh + (size_t)row * H_DIM + (c * 256 + lane * 4));
        #pragma unroll
        for (int c = 0; c < 2; ++c)
            wx[g][c] = *(const float4*)(W_ih + (size_t)row * IN_DIM + (c * 256 + lane * 4));
        bias_g[g] = b_ih[row] + b_hh[row];
    }

    // per-thread poll bases into THIS WG's replica: two contiguous 4KB
    // blocks per parity buffer; thread tid reads 16B from each block.
    const u32* repbase = (const u32*)(hbuf + (size_t)rep * 2 * H_DIM);
    // parity p buffer starts at repbase + p*2048 (u32 units: H_DIM u64 = 2048 u32)
    // block 1: + tid*4 ; block 2: + 1024 + tid*4

    float c_state = 0.0f;   // cell state for `elem` (consistent across lanes)

    for (int t = 0; t < T_STEPS; ++t) {
        const int p = t & 1;

        // ---- stage x[t] into LDS (issue global load before the spin) ----
        // This pre-poll fetch is LOAD-BEARING (R6): it delays the first
        // poll sample until producer stores are visible.
        const float2 xv = *(const float2*)(X + (size_t)t * IN_DIM + tid * 2);
        *(float2*)(&x_lds[p][tid * 2]) = xv;

        // ---- poll h[t]: two contiguous 16B loads per thread ----
        {
            const u32* s1 = repbase + (size_t)p * 2048 + tid * 4;
            const u32* s2 = s1 + 1024;
            const u32 tu = (u32)t;
            u32x4 a, b4;
            for (;;) {
                asm volatile(
                    "global_load_dwordx4 %0, %2, off sc0 sc1\n\t"
                    "global_load_dwordx4 %1, %3, off sc0 sc1\n\t"
                    "s_waitcnt vmcnt(0)"
                    : "=&v"(a), "=&v"(b4)
                    : "v"(s1), "v"(s2)
                    : "memory");
                // dwords: [val0, tag0, val1, tag1]
                if ((((a[1] ^ tu) | (a[3] ^ tu)) | ((b4[1] ^ tu) | (b4[3] ^ tu))) == 0u)
                    break;
            }
            // block1 -> elements {2tid, 2tid+1}; block2 -> {512+2tid, 512+2tid+1}
            h_lds[p][2 * tid + 0]       = __uint_as_float(a[0]);
            h_lds[p][2 * tid + 1]       = __uint_as_float(a[2]);
            h_lds[p][512 + 2 * tid + 0] = __uint_as_float(b4[0]);
            h_lds[p][512 + 2 * tid + 1] = __uint_as_float(b4[2]);
        }
        __syncthreads();   // single barrier per step: staging complete

        // ---- 4 gate dot-products for `elem` ----
        float acc0 = 0.f, acc1 = 0.f, acc2 = 0.f, acc3 = 0.f;
        const float4* h4 = (const float4*)(&h_lds[p][0]);
        const float4* x4 = (const float4*)(&x_lds[p][0]);
        #pragma unroll
        for (int c = 0; c < 4; ++c) {
            const float4 hv = h4[c * 64 + lane];
            acc0 += wh[0][c].x*hv.x + wh[0][c].y*hv.y + wh[0][c].z*hv.z + wh[0][c].w*hv.w;
            acc1 += wh[1][c].x*hv.x + wh[1][c].y*hv.y + wh[1][c].z*hv.z + wh[1][c].w*hv.w;
            acc2 += wh[2][c].x*hv.x + wh[2][c].y*hv.y + wh[2][c].z*hv.z + wh[2][c].w*hv.w;
            acc3 += wh[3][c].x*hv.x + wh[3][c].y*hv.y + wh[3][c].z*hv.z + wh[3][c].w*hv.w;
        }
        #pragma unroll
        for (int c = 0; c < 2; ++c) {
            const float4 qv = x4[c * 64 + lane];
            acc0 += wx[0][c].x*qv.x + wx[0][c].y*qv.y + wx[0][c].z*qv.z + wx[0][c].w*qv.w;
            acc1 += wx[1][c].x*qv.x + wx[1][c].y*qv.y + wx[1][c].z*qv.z + wx[1][c].w*qv.w;
            acc2 += wx[2][c].x*qv.x + wx[2][c].y*qv.y + wx[2][c].z*qv.z + wx[2][c].w*qv.w;
            acc3 += wx[3][c].x*qv.x + wx[3][c].y*qv.y + wx[3][c].z*qv.z + wx[3][c].w*qv.w;
        }

        // ---- full-wave butterfly reduce (all lanes end with the sums) ----
        #pragma unroll
        for (int off = 32; off >= 1; off >>= 1) {
            acc0 += __shfl_xor(acc0, off);
            acc1 += __shfl_xor(acc1, off);
            acc2 += __shfl_xor(acc2, off);
            acc3 += __shfl_xor(acc3, off);
        }

        // ---- combine (all lanes compute; avoids divergent exec region) ----
        const float ii = sigf(acc0 + bias_g[0]);
        const float ff = sigf(acc1 + bias_g[1]);
        const float gg = tanh_fast(acc2 + bias_g[2]);
        const float oo = sigf(acc3 + bias_g[3]);
        const float cn = ff * c_state + ii * gg;
        c_state = cn;
        const float hn = oo * tanh_fast(cn);

        if (lane == 0) {
            const u64 word = ((u64)(unsigned)(t + 1) << 32)
                           | (u64)__float_as_uint(hn);
            u64* dst = hbuf + (size_t)((t + 1) & 1) * H_DIM + elem;
            #pragma unroll
            for (int r = 0; r < NREP; ++r)
                __hip_atomic_store(dst + (size_t)r * 2 * H_DIM, word,
                                   __ATOMIC_RELAXED, __HIP_MEMORY_SCOPE_AGENT);
        }
        // No second barrier needed: next-step staging writes parity (t+1)&1,
        // disjoint from this step's reads; tag protocol covers parity reuse.
    }
}

__global__ __launch_bounds__(256, 1) void lstm_head(
    const u64* __restrict__ hbuf,
    const float* __restrict__ W_lin,
    const float* __restrict__ b_lin,
    float* __restrict__ out)
{
    const int tid  = threadIdx.x;
    const int o    = tid >> 2;       // output index, 4 threads per output
    const int part = tid & 3;
    // replica 0, parity (T&1)=0 holds h_T
    const u64* src = hbuf + (size_t)(T_STEPS & 1) * H_DIM;

    float sum = 0.f;
    const int k0 = part * 256;
    for (int k = k0; k < k0 + 256; k += 4) {
        const float4 wv = *(const float4*)(W_lin + (size_t)o * H_DIM + k);
        sum += wv.x * __uint_as_float((unsigned)src[k + 0])
             + wv.y * __uint_as_float((unsigned)src[k + 1])
             + wv.z * __uint_as_float((unsigned)src[k + 2])
             + wv.w * __uint_as_float((unsigned)src[k + 3]);
    }
    sum += __shfl_xor(sum, 1);
    sum += __shfl_xor(sum, 2);
    if (part == 0)
        out[o] = 1.0f / (1.0f + __expf(-(sum + b_lin[o])));
}

extern "C" void kernel_launch(void* const* d_in, const int* in_sizes, int n_in,
                              void* d_out, int out_size, void* d_ws, size_t ws_size,
                              hipStream_t stream) {
    const float* X     = (const float*)d_in[0];
    // d_in[1] Mask, d_in[2] Delta, d_in[3] dt: unused by the forward pass
    const float* W_ih  = (const float*)d_in[4];
    const float* W_hh  = (const float*)d_in[5];
    const float* b_ih  = (const float*)d_in[6];
    const float* b_hh  = (const float*)d_in[7];
    const float* W_lin = (const float*)d_in[8];
    const float* b_lin = (const float*)d_in[9];
    float* out = (float*)d_out;

    u64* hbuf = (u64*)d_ws;   // NREP * 2 * 1024 * 8B = 128 KiB used

    // init: all replicas, both parity buffers = {tag=0, h=0.0f}
    hipMemsetAsync(hbuf, 0, NREP * 2 * H_DIM * sizeof(u64), stream);

    lstm_seq<<<NWG, 256, 0, stream>>>(X, W_ih, W_hh, b_ih, b_hh, hbuf);
    lstm_head<<<1, 256, 0, stream>>>(hbuf, W_lin, b_lin, out);
}

// Round 8
// 27625.391 us; speedup vs baseline: 2.5581x; 1.1271x over previous
//
#include <hip/hip_runtime.h>
#include <stdint.h>

// TLSTM: batch-1 LSTM, T=16384 steps, IN=512, H=1024, OUT=64.
// Persistent-kernel design: 256 WGs (one per CU). WG b owns h-elements
// {4b..4b+3}; wave w owns element 4b+w and computes all 4 gate rows for
// it; weights live in registers (96 floats/lane, loaded once). Cross-WG
// exchange of h each step through a tagged 64-bit {step, value} word per
// h-element in d_ws, double-buffered by step parity.
//
// Experiment ledger:
//   R1: coalesced 2x16B poll sweeps           35.0 -> 29.0 ms  [BEST]
//   R2: pipelined vmcnt poll + x-in-regs      -> 90+ ms (foreign HBM
//       loads inside the poll's counted-vmcnt window)
//   R3: 4B words (8KB footprint)              -> 36.5 ms
//   R4: s_sleep-paced poll                    -> 29.0 ms == R1 (pacing
//       and extra pre-poll delay are FREE; poll is latency-bound)
//   R5: A/B counted-vmcnt(2) poll             -> crashed; abandoned
//   R6: x-staging moved off pre-poll path     -> 67.6 ms (pre-poll
//       x-load delay is LOAD-BEARING: first sample must land after
//       producer stores are visible)
//   R7: 8x replica + contiguous sweep         -> 31.1 ms, FETCH
//       unchanged == R1 -> consumer-side spreading does NOTHING; the
//       exchange is a fixed-latency rendezvous at its floor. The +2ms
//       was the 8-store producer fan-out.
// R8 (this): exchange structure byte-identical to R1. Single change:
// the h-independent x-projection moves BEFORE the poll. Each lane loads
// its own two x float4 fragments (cached; X row is L2/L1-resident since
// all WGs read it) and runs its 32 x-FMAs pre-poll -- preserving the
// load-bearing delay (x-load latency + ~70cy FMA issue; extra delay
// proven free by R4) while deleting x_lds and removing 2 LDS reads +
// 32 FMAs from the post-barrier critical path.

typedef unsigned long long u64;
typedef uint32_t u32x4 __attribute__((ext_vector_type(4)));

#define T_STEPS 16384
#define IN_DIM  512
#define H_DIM   1024
#define OUT_DIM 64
#define NWG     256

__device__ __forceinline__ float sigf(float x) {
    return 1.0f / (1.0f + __expf(-x));
}
__device__ __forceinline__ float tanh_fast(float x) {
    // tanh(x) = 2*sigmoid(2x) - 1 ; |err| ~1e-7 rel with __expf
    return 2.0f / (1.0f + __expf(-2.0f * x)) - 1.0f;
}

__global__ __launch_bounds__(256, 1) void lstm_seq(
    const float* __restrict__ X,
    const float* __restrict__ W_ih,
    const float* __restrict__ W_hh,
    const float* __restrict__ b_ih,
    const float* __restrict__ b_hh,
    u64* __restrict__ hbuf)   // [2][H_DIM] tagged words in d_ws
{
    const int b    = blockIdx.x;      // 0..255
    const int tid  = threadIdx.x;     // 0..255
    const int w    = tid >> 6;        // wave id == owned element index j
    const int lane = tid & 63;
    const int elem = 4 * b + w;       // global h index this wave produces

    __shared__ float h_lds[2][H_DIM];

    // ---- one-time: weights into registers ----
    // lane covers k = c*256 + lane*4 + {0..3}  (contiguous float4, coalesced
    // global loads and conflict-free ds_read_b128 later).
    float4 wh[4][4];   // [gate][chunk]  over H_DIM=1024
    float4 wx[4][2];   // [gate][chunk]  over IN_DIM=512
    float  bias_g[4];
    #pragma unroll
    for (int g = 0; g < 4; ++g) {
        const int row = g * H_DIM + elem;
        #pragma unroll
        for (int c = 0; c < 4; ++c)
            wh[g][c] = *(const float4*)(W_hh + (size_t)row * H_DIM + (c * 256 + lane * 4));
        #pragma unroll
        for (int c = 0; c < 2; ++c)
            wx[g][c] = *(const float4*)(W_ih + (size_t)row * IN_DIM + (c * 256 + lane * 4));
        bias_g[g] = b_ih[row] + b_hh[row];
    }

    // per-thread poll bases for the two parity buffers (4 tagged words = 32B)
    const uint32_t* poll0 = (const uint32_t*)(hbuf + (size_t)tid * 4);
    const uint32_t* poll1 = (const uint32_t*)(hbuf + (size_t)H_DIM + (size_t)tid * 4);

    float c_state = 0.0f;   // cell state for `elem` (consistent across lanes)

    for (int t = 0; t < T_STEPS; ++t) {
        const int p = t & 1;

        // ---- per-lane x fragments + x-gate partials, BEFORE the poll ----
        // The x-load latency is the load-bearing pre-poll delay (R6); the
        // 32 FMAs extend it slightly (free per R4) and come OFF the
        // post-barrier critical path. Cached loads: X row is read by all
        // 256 WGs -> L2-resident; 4 waves share lines via L1.
        const float4 xv0 = *(const float4*)(X + (size_t)t * IN_DIM + lane * 4);
        const float4 xv1 = *(const float4*)(X + (size_t)t * IN_DIM + 256 + lane * 4);
        float acc0, acc1, acc2, acc3;
        acc0 = wx[0][0].x*xv0.x + wx[0][0].y*xv0.y + wx[0][0].z*xv0.z + wx[0][0].w*xv0.w
             + wx[0][1].x*xv1.x + wx[0][1].y*xv1.y + wx[0][1].z*xv1.z + wx[0][1].w*xv1.w;
        acc1 = wx[1][0].x*xv0.x + wx[1][0].y*xv0.y + wx[1][0].z*xv0.z + wx[1][0].w*xv0.w
             + wx[1][1].x*xv1.x + wx[1][1].y*xv1.y + wx[1][1].z*xv1.z + wx[1][1].w*xv1.w;
        acc2 = wx[2][0].x*xv0.x + wx[2][0].y*xv0.y + wx[2][0].z*xv0.z + wx[2][0].w*xv0.w
             + wx[2][1].x*xv1.x + wx[2][1].y*xv1.y + wx[2][1].z*xv1.z + wx[2][1].w*xv1.w;
        acc3 = wx[3][0].x*xv0.x + wx[3][0].y*xv0.y + wx[3][0].z*xv0.z + wx[3][0].w*xv0.w
             + wx[3][1].x*xv1.x + wx[3][1].y*xv1.y + wx[3][1].z*xv1.z + wx[3][1].w*xv1.w;
        // Pin the partials as materialized HERE: stops the compiler sinking
        // these FMAs past the poll (which would re-lengthen the post-barrier
        // path and could entangle the x loads with the poll's vmcnt).
        asm volatile("" : "+v"(acc0), "+v"(acc1), "+v"(acc2), "+v"(acc3));

        // ---- poll h[t]: R1-exact single-slot poll ----
        {
            const uint32_t* src = p ? poll1 : poll0;
            const uint32_t tu = (uint32_t)t;
            u32x4 a, b4;
            for (;;) {
                asm volatile(
                    "global_load_dwordx4 %0, %2, off sc0 sc1\n\t"
                    "global_load_dwordx4 %1, %2, off offset:16 sc0 sc1\n\t"
                    "s_waitcnt vmcnt(0)"
                    : "=&v"(a), "=&v"(b4)
                    : "v"(src)
                    : "memory");
                // dwords: [val0, tag0, val1, tag1]
                if ((((a[1] ^ tu) | (a[3] ^ tu)) | ((b4[1] ^ tu) | (b4[3] ^ tu))) == 0u)
                    break;
            }
            h_lds[p][tid * 4 + 0] = __uint_as_float(a[0]);
            h_lds[p][tid * 4 + 1] = __uint_as_float(a[2]);
            h_lds[p][tid * 4 + 2] = __uint_as_float(b4[0]);
            h_lds[p][tid * 4 + 3] = __uint_as_float(b4[2]);
        }
        __syncthreads();   // single barrier per step: h staging complete

        // ---- 4 gate dot-products over h for `elem` (x already folded) ----
        const float4* h4 = (const float4*)(&h_lds[p][0]);
        #pragma unroll
        for (int c = 0; c < 4; ++c) {
            const float4 hv = h4[c * 64 + lane];
            acc0 += wh[0][c].x*hv.x + wh[0][c].y*hv.y + wh[0][c].z*hv.z + wh[0][c].w*hv.w;
            acc1 += wh[1][c].x*hv.x + wh[1][c].y*hv.y + wh[1][c].z*hv.z + wh[1][c].w*hv.w;
            acc2 += wh[2][c].x*hv.x + wh[2][c].y*hv.y + wh[2][c].z*hv.z + wh[2][c].w*hv.w;
            acc3 += wh[3][c].x*hv.x + wh[3][c].y*hv.y + wh[3][c].z*hv.z + wh[3][c].w*hv.w;
        }

        // ---- full-wave butterfly reduce (all lanes end with the sums) ----
        #pragma unroll
        for (int off = 32; off >= 1; off >>= 1) {
            acc0 += __shfl_xor(acc0, off);
            acc1 += __shfl_xor(acc1, off);
            acc2 += __shfl_xor(acc2, off);
            acc3 += __shfl_xor(acc3, off);
        }

        // ---- combine (all lanes compute; avoids divergent exec region) ----
        const float ii = sigf(acc0 + bias_g[0]);
        const float ff = sigf(acc1 + bias_g[1]);
        const float gg = tanh_fast(acc2 + bias_g[2]);
        const float oo = sigf(acc3 + bias_g[3]);
        const float cn = ff * c_state + ii * gg;
        c_state = cn;
        const float hn = oo * tanh_fast(cn);

        if (lane == 0) {
            const u64 word = ((u64)(unsigned)(t + 1) << 32)
                           | (u64)__float_as_uint(hn);
            __hip_atomic_store(hbuf + (size_t)((t + 1) & 1) * H_DIM + elem,
                               word, __ATOMIC_RELAXED, __HIP_MEMORY_SCOPE_AGENT);
        }
        // No second barrier needed: next-step staging writes parity (t+1)&1,
        // disjoint from this step's reads; tag protocol covers parity reuse.
    }
}

__global__ __launch_bounds__(256, 1) void lstm_head(
    const u64* __restrict__ hbuf,
    const float* __restrict__ W_lin,
    const float* __restrict__ b_lin,
    float* __restrict__ out)
{
    const int tid  = threadIdx.x;
    const int o    = tid >> 2;       // output index, 4 threads per output
    const int part = tid & 3;
    const u64* src = hbuf + (size_t)(T_STEPS & 1) * H_DIM;  // buf[0]: tag T

    float sum = 0.f;
    const int k0 = part * 256;
    for (int k = k0; k < k0 + 256; k += 4) {
        const float4 wv = *(const float4*)(W_lin + (size_t)o * H_DIM + k);
        sum += wv.x * __uint_as_float((unsigned)src[k + 0])
             + wv.y * __uint_as_float((unsigned)src[k + 1])
             + wv.z * __uint_as_float((unsigned)src[k + 2])
             + wv.w * __uint_as_float((unsigned)src[k + 3]);
    }
    sum += __shfl_xor(sum, 1);
    sum += __shfl_xor(sum, 2);
    if (part == 0)
        out[o] = 1.0f / (1.0f + __expf(-(sum + b_lin[o])));
}

extern "C" void kernel_launch(void* const* d_in, const int* in_sizes, int n_in,
                              void* d_out, int out_size, void* d_ws, size_t ws_size,
                              hipStream_t stream) {
    const float* X     = (const float*)d_in[0];
    // d_in[1] Mask, d_in[2] Delta, d_in[3] dt: unused by the forward pass
    const float* W_ih  = (const float*)d_in[4];
    const float* W_hh  = (const float*)d_in[5];
    const float* b_ih  = (const float*)d_in[6];
    const float* b_hh  = (const float*)d_in[7];
    const float* W_lin = (const float*)d_in[8];
    const float* b_lin = (const float*)d_in[9];
    float* out = (float*)d_out;

    u64* hbuf = (u64*)d_ws;   // 2 * 1024 * 8B = 16 KiB used

    // init: both parity buffers = {tag=0, h=0.0f} (all zero bytes)
    hipMemsetAsync(hbuf, 0, 2 * H_DIM * sizeof(u64), stream);

    lstm_seq<<<NWG, 256, 0, stream>>>(X, W_ih, W_hh, b_ih, b_hh, hbuf);
    lstm_head<<<1, 256, 0, stream>>>(hbuf, W_lin, b_lin, out);
}

// Round 9
// 24111.453 us; speedup vs baseline: 2.9310x; 1.1457x over previous
//
#include <hip/hip_runtime.h>
#include <stdint.h>

// TLSTM: batch-1 LSTM, T=16384 steps, IN=512, H=1024, OUT=64.
// Persistent-kernel design: 256 WGs (one per CU). WG b owns h-elements
// {4b..4b+3}; wave w owns element 4b+w and computes all 4 gate rows for
// it; weights live in registers (96 floats/lane, loaded once). Cross-WG
// exchange of h each step through a tagged 64-bit {step, value} word per
// h-element in d_ws, double-buffered by step parity.
//
// Experiment ledger:
//   R1: coalesced 2x16B poll sweeps           35.0 -> 29.0 ms
//   R2: pipelined vmcnt poll                  -> 90+ ms (foreign HBM
//       loads inside the poll's counted-vmcnt window)
//   R3: 4B words (8KB footprint)              -> 36.5 ms
//   R4: s_sleep-paced poll                    -> 29.0 == R1 (pre-poll
//       delay is free; poll is latency-bound)
//   R5: A/B counted-vmcnt(2) poll             -> crashed; abandoned
//   R6: x-staging off pre-poll path           -> 67.6 ms (pre-poll
//       x-load delay is LOAD-BEARING for first-sample timing)
//   R7: 8x replica + contiguous sweep         -> 31.1 ms (consumer-side
//       spreading does nothing; exchange = fixed-latency rendezvous)
//   R8: x-projection moved pre-poll           29.0 -> 27.6 ms [matched
//       prediction: serial compute around the rendezvous is the
//       remaining addressable term]
// R9 (this): replace the 24-op __shfl_xor butterfly (6 serial
// ds_bpermute levels, ~300cy on the LDS pipe) with the canonical DPP
// reduction: v_add_f32_dpp row_shr 1/2/4/8 + row_bcast:15 (rows 1,3) +
// row_bcast:31 (rows 2,3). Pure VALU, 4 chains interleaved (gives the
// >=2-inst spacing the VALU-write->DPP-read hazard needs), ~60-80cy.
// Sum lands in LANE 63 -> lane 63 is now the producer lane; c_state is
// only meaningful there (other lanes' gate values are garbage that is
// never stored or communicated).

typedef unsigned long long u64;
typedef uint32_t u32x4 __attribute__((ext_vector_type(4)));

#define T_STEPS 16384
#define IN_DIM  512
#define H_DIM   1024
#define OUT_DIM 64
#define NWG     256

__device__ __forceinline__ float sigf(float x) {
    return 1.0f / (1.0f + __expf(-x));
}
__device__ __forceinline__ float tanh_fast(float x) {
    // tanh(x) = 2*sigmoid(2x) - 1 ; |err| ~1e-7 rel with __expf
    return 2.0f / (1.0f + __expf(-2.0f * x)) - 1.0f;
}

__global__ __launch_bounds__(256, 1) void lstm_seq(
    const float* __restrict__ X,
    const float* __restrict__ W_ih,
    const float* __restrict__ W_hh,
    const float* __restrict__ b_ih,
    const float* __restrict__ b_hh,
    u64* __restrict__ hbuf)   // [2][H_DIM] tagged words in d_ws
{
    const int b    = blockIdx.x;      // 0..255
    const int tid  = threadIdx.x;     // 0..255
    const int w    = tid >> 6;        // wave id == owned element index j
    const int lane = tid & 63;
    const int elem = 4 * b + w;       // global h index this wave produces

    __shared__ float h_lds[2][H_DIM];

    // ---- one-time: weights into registers ----
    float4 wh[4][4];   // [gate][chunk]  over H_DIM=1024
    float4 wx[4][2];   // [gate][chunk]  over IN_DIM=512
    float  bias_g[4];
    #pragma unroll
    for (int g = 0; g < 4; ++g) {
        const int row = g * H_DIM + elem;
        #pragma unroll
        for (int c = 0; c < 4; ++c)
            wh[g][c] = *(const float4*)(W_hh + (size_t)row * H_DIM + (c * 256 + lane * 4));
        #pragma unroll
        for (int c = 0; c < 2; ++c)
            wx[g][c] = *(const float4*)(W_ih + (size_t)row * IN_DIM + (c * 256 + lane * 4));
        bias_g[g] = b_ih[row] + b_hh[row];
    }

    // per-thread poll bases for the two parity buffers (4 tagged words = 32B)
    const uint32_t* poll0 = (const uint32_t*)(hbuf + (size_t)tid * 4);
    const uint32_t* poll1 = (const uint32_t*)(hbuf + (size_t)H_DIM + (size_t)tid * 4);

    float c_state = 0.0f;   // cell state for `elem` (valid on lane 63 only)

    for (int t = 0; t < T_STEPS; ++t) {
        const int p = t & 1;

        // ---- per-lane x fragments + x-gate partials, BEFORE the poll ----
        // (R8: load-bearing pre-poll delay + off the post-barrier path)
        const float4 xv0 = *(const float4*)(X + (size_t)t * IN_DIM + lane * 4);
        const float4 xv1 = *(const float4*)(X + (size_t)t * IN_DIM + 256 + lane * 4);
        float acc0, acc1, acc2, acc3;
        acc0 = wx[0][0].x*xv0.x + wx[0][0].y*xv0.y + wx[0][0].z*xv0.z + wx[0][0].w*xv0.w
             + wx[0][1].x*xv1.x + wx[0][1].y*xv1.y + wx[0][1].z*xv1.z + wx[0][1].w*xv1.w;
        acc1 = wx[1][0].x*xv0.x + wx[1][0].y*xv0.y + wx[1][0].z*xv0.z + wx[1][0].w*xv0.w
             + wx[1][1].x*xv1.x + wx[1][1].y*xv1.y + wx[1][1].z*xv1.z + wx[1][1].w*xv1.w;
        acc2 = wx[2][0].x*xv0.x + wx[2][0].y*xv0.y + wx[2][0].z*xv0.z + wx[2][0].w*xv0.w
             + wx[2][1].x*xv1.x + wx[2][1].y*xv1.y + wx[2][1].z*xv1.z + wx[2][1].w*xv1.w;
        acc3 = wx[3][0].x*xv0.x + wx[3][0].y*xv0.y + wx[3][0].z*xv0.z + wx[3][0].w*xv0.w
             + wx[3][1].x*xv1.x + wx[3][1].y*xv1.y + wx[3][1].z*xv1.z + wx[3][1].w*xv1.w;
        asm volatile("" : "+v"(acc0), "+v"(acc1), "+v"(acc2), "+v"(acc3));

        // ---- poll h[t]: R1-exact single-slot poll ----
        {
            const uint32_t* src = p ? poll1 : poll0;
            const uint32_t tu = (uint32_t)t;
            u32x4 a, b4;
            for (;;) {
                asm volatile(
                    "global_load_dwordx4 %0, %2, off sc0 sc1\n\t"
                    "global_load_dwordx4 %1, %2, off offset:16 sc0 sc1\n\t"
                    "s_waitcnt vmcnt(0)"
                    : "=&v"(a), "=&v"(b4)
                    : "v"(src)
                    : "memory");
                if ((((a[1] ^ tu) | (a[3] ^ tu)) | ((b4[1] ^ tu) | (b4[3] ^ tu))) == 0u)
                    break;
            }
            h_lds[p][tid * 4 + 0] = __uint_as_float(a[0]);
            h_lds[p][tid * 4 + 1] = __uint_as_float(a[2]);
            h_lds[p][tid * 4 + 2] = __uint_as_float(b4[0]);
            h_lds[p][tid * 4 + 3] = __uint_as_float(b4[2]);
        }
        __syncthreads();   // single barrier per step: h staging complete

        // ---- 4 gate dot-products over h for `elem` (x already folded) ----
        const float4* h4 = (const float4*)(&h_lds[p][0]);
        #pragma unroll
        for (int c = 0; c < 4; ++c) {
            const float4 hv = h4[c * 64 + lane];
            acc0 += wh[0][c].x*hv.x + wh[0][c].y*hv.y + wh[0][c].z*hv.z + wh[0][c].w*hv.w;
            acc1 += wh[1][c].x*hv.x + wh[1][c].y*hv.y + wh[1][c].z*hv.z + wh[1][c].w*hv.w;
            acc2 += wh[2][c].x*hv.x + wh[2][c].y*hv.y + wh[2][c].z*hv.z + wh[2][c].w*hv.w;
            acc3 += wh[3][c].x*hv.x + wh[3][c].y*hv.y + wh[3][c].z*hv.z + wh[3][c].w*hv.w;
        }

        // ---- DPP wave reduction: 4 interleaved chains, sum -> lane 63 ----
        // row_shr 1/2/4/8 build each 16-lane row sum into lane 15 of the
        // row; row_bcast:15 (rows 1,3) folds row-pairs into lanes 31/63;
        // row_bcast:31 (rows 2,3) folds halves into lane 63. bound_ctrl:0
        // zero-fills out-of-range reads. Interleaving 4 chains spaces each
        // VALU-write >=3 insts from its DPP read (hazard requirement).
        asm volatile(
            "v_add_f32_dpp %0, %0, %0 row_shr:1 row_mask:0xf bank_mask:0xf bound_ctrl:0\n\t"
            "v_add_f32_dpp %1, %1, %1 row_shr:1 row_mask:0xf bank_mask:0xf bound_ctrl:0\n\t"
            "v_add_f32_dpp %2, %2, %2 row_shr:1 row_mask:0xf bank_mask:0xf bound_ctrl:0\n\t"
            "v_add_f32_dpp %3, %3, %3 row_shr:1 row_mask:0xf bank_mask:0xf bound_ctrl:0\n\t"
            "v_add_f32_dpp %0, %0, %0 row_shr:2 row_mask:0xf bank_mask:0xf bound_ctrl:0\n\t"
            "v_add_f32_dpp %1, %1, %1 row_shr:2 row_mask:0xf bank_mask:0xf bound_ctrl:0\n\t"
            "v_add_f32_dpp %2, %2, %2 row_shr:2 row_mask:0xf bank_mask:0xf bound_ctrl:0\n\t"
            "v_add_f32_dpp %3, %3, %3 row_shr:2 row_mask:0xf bank_mask:0xf bound_ctrl:0\n\t"
            "v_add_f32_dpp %0, %0, %0 row_shr:4 row_mask:0xf bank_mask:0xf bound_ctrl:0\n\t"
            "v_add_f32_dpp %1, %1, %1 row_shr:4 row_mask:0xf bank_mask:0xf bound_ctrl:0\n\t"
            "v_add_f32_dpp %2, %2, %2 row_shr:4 row_mask:0xf bank_mask:0xf bound_ctrl:0\n\t"
            "v_add_f32_dpp %3, %3, %3 row_shr:4 row_mask:0xf bank_mask:0xf bound_ctrl:0\n\t"
            "v_add_f32_dpp %0, %0, %0 row_shr:8 row_mask:0xf bank_mask:0xf bound_ctrl:0\n\t"
            "v_add_f32_dpp %1, %1, %1 row_shr:8 row_mask:0xf bank_mask:0xf bound_ctrl:0\n\t"
            "v_add_f32_dpp %2, %2, %2 row_shr:8 row_mask:0xf bank_mask:0xf bound_ctrl:0\n\t"
            "v_add_f32_dpp %3, %3, %3 row_shr:8 row_mask:0xf bank_mask:0xf bound_ctrl:0\n\t"
            "v_add_f32_dpp %0, %0, %0 row_bcast:15 row_mask:0xa bank_mask:0xf bound_ctrl:0\n\t"
            "v_add_f32_dpp %1, %1, %1 row_bcast:15 row_mask:0xa bank_mask:0xf bound_ctrl:0\n\t"
            "v_add_f32_dpp %2, %2, %2 row_bcast:15 row_mask:0xa bank_mask:0xf bound_ctrl:0\n\t"
            "v_add_f32_dpp %3, %3, %3 row_bcast:15 row_mask:0xa bank_mask:0xf bound_ctrl:0\n\t"
            "v_add_f32_dpp %0, %0, %0 row_bcast:31 row_mask:0xc bank_mask:0xf bound_ctrl:0\n\t"
            "v_add_f32_dpp %1, %1, %1 row_bcast:31 row_mask:0xc bank_mask:0xf bound_ctrl:0\n\t"
            "v_add_f32_dpp %2, %2, %2 row_bcast:31 row_mask:0xc bank_mask:0xf bound_ctrl:0\n\t"
            "v_add_f32_dpp %3, %3, %3 row_bcast:31 row_mask:0xc bank_mask:0xf bound_ctrl:0"
            : "+v"(acc0), "+v"(acc1), "+v"(acc2), "+v"(acc3));

        // ---- combine: only lane 63 holds the true sums; other lanes
        //      compute garbage that is never stored or communicated ----
        const float ii = sigf(acc0 + bias_g[0]);
        const float ff = sigf(acc1 + bias_g[1]);
        const float gg = tanh_fast(acc2 + bias_g[2]);
        const float oo = sigf(acc3 + bias_g[3]);
        const float cn = ff * c_state + ii * gg;
        c_state = cn;
        const float hn = oo * tanh_fast(cn);

        if (lane == 63) {
            const u64 word = ((u64)(unsigned)(t + 1) << 32)
                           | (u64)__float_as_uint(hn);
            __hip_atomic_store(hbuf + (size_t)((t + 1) & 1) * H_DIM + elem,
                               word, __ATOMIC_RELAXED, __HIP_MEMORY_SCOPE_AGENT);
        }
        // No second barrier needed: next-step staging writes parity (t+1)&1,
        // disjoint from this step's reads; tag protocol covers parity reuse.
    }
}

__global__ __launch_bounds__(256, 1) void lstm_head(
    const u64* __restrict__ hbuf,
    const float* __restrict__ W_lin,
    const float* __restrict__ b_lin,
    float* __restrict__ out)
{
    const int tid  = threadIdx.x;
    const int o    = tid >> 2;       // output index, 4 threads per output
    const int part = tid & 3;
    const u64* src = hbuf + (size_t)(T_STEPS & 1) * H_DIM;  // buf[0]: tag T

    float sum = 0.f;
    const int k0 = part * 256;
    for (int k = k0; k < k0 + 256; k += 4) {
        const float4 wv = *(const float4*)(W_lin + (size_t)o * H_DIM + k);
        sum += wv.x * __uint_as_float((unsigned)src[k + 0])
             + wv.y * __uint_as_float((unsigned)src[k + 1])
             + wv.z * __uint_as_float((unsigned)src[k + 2])
             + wv.w * __uint_as_float((unsigned)src[k + 3]);
    }
    sum += __shfl_xor(sum, 1);
    sum += __shfl_xor(sum, 2);
    if (part == 0)
        out[o] = 1.0f / (1.0f + __expf(-(sum + b_lin[o])));
}

extern "C" void kernel_launch(void* const* d_in, const int* in_sizes, int n_in,
                              void* d_out, int out_size, void* d_ws, size_t ws_size,
                              hipStream_t stream) {
    const float* X     = (const float*)d_in[0];
    // d_in[1] Mask, d_in[2] Delta, d_in[3] dt: unused by the forward pass
    const float* W_ih  = (const float*)d_in[4];
    const float* W_hh  = (const float*)d_in[5];
    const float* b_ih  = (const float*)d_in[6];
    const float* b_hh  = (const float*)d_in[7];
    const float* W_lin = (const float*)d_in[8];
    const float* b_lin = (const float*)d_in[9];
    float* out = (float*)d_out;

    u64* hbuf = (u64*)d_ws;   // 2 * 1024 * 8B = 16 KiB used

    // init: both parity buffers = {tag=0, h=0.0f} (all zero bytes)
    hipMemsetAsync(hbuf, 0, 2 * H_DIM * sizeof(u64), stream);

    lstm_seq<<<NWG, 256, 0, stream>>>(X, W_ih, W_hh, b_ih, b_hh, hbuf);
    lstm_head<<<1, 256, 0, stream>>>(hbuf, W_lin, b_lin, out);
}